// Round 12
// baseline (297.026 us; speedup 1.0000x reference)
//
#include <hip/hip_runtime.h>
#include <hip/hip_bf16.h>

// Problem constants
#define B_   4
#define T_   32
#define N_   370
#define NP_  384            // N_ padded to 384 for dense-A MFMA
#define E_   11840
#define E2_  12210          // E_ + N_ self loops
#define H_   64
#define G_   128            // B_*T_
#define GN_  47360          // G_*N_
#define BN_  1480           // B_*N_
#define NH_  23680          // N_*H_
#define ECAP 320            // LDS edge-stage capacity per node (max deg ~70)
#define KCH_ 128            // mlp1 MFMA k-chunk (23680 = 128*185)
#define NCH_ 185            // number of k-chunks

typedef __hip_bfloat16 bf;
typedef short short8 __attribute__((ext_vector_type(8)));
typedef float f32x4 __attribute__((ext_vector_type(4)));

__device__ __forceinline__ float gelu_f(float x){
  return 0.5f * x * (1.0f + erff(x * 0.7071067811865475f));
}
__device__ __forceinline__ float lrelu(float v){ return v > 0.f ? v : 0.2f * v; }
__device__ __forceinline__ float b2f(bf x){ return __bfloat162float(x); }
__device__ __forceinline__ void store_bf4(bf* p, float4 v){
  bf tmp[4] = {__float2bfloat16(v.x), __float2bfloat16(v.y),
               __float2bfloat16(v.z), __float2bfloat16(v.w)};
  *(ushort4*)p = *(const ushort4*)tmp;
}
__device__ __forceinline__ unsigned pk_bf2(float a, float b){
  bf lo = __float2bfloat16(a), hi = __float2bfloat16(b);
  return (unsigned)*(unsigned short*)&lo | ((unsigned)*(unsigned short*)&hi << 16);
}
// load 8 consecutive bf16 (16B aligned) -> 8 floats
__device__ __forceinline__ void load_bf8(const bf* p, float* v){
  uint4 u = *(const uint4*)p;
  unsigned ua[4] = {u.x, u.y, u.z, u.w};
  #pragma unroll
  for (int i = 0; i < 4; ++i){
    v[2*i]   = __uint_as_float(ua[i] << 16);
    v[2*i+1] = __uint_as_float(ua[i] & 0xffff0000u);
  }
}

// ---------- edge preprocessing ----------
// single block: deg/count LDS atomics + exclusive scan
__global__ __launch_bounds__(1024) void k_degscan(const int* __restrict__ ei,
    const float* __restrict__ ew, float* __restrict__ degG,
    int* __restrict__ offs, int* __restrict__ cursor){
  __shared__ float degS[512];
  __shared__ int cntS[512];
  int tid = threadIdx.x;
  if (tid < 512){ degS[tid] = 0.f; cntS[tid] = 0; }
  __syncthreads();
  for (int e = tid; e < E2_; e += 1024){
    int dst = (e < E_) ? ei[E_ + e] : (e - E_);
    float w = (e < E_) ? ew[e] : 1.0f;
    atomicAdd(&degS[dst], w);
    atomicAdd(&cntS[dst], 1);
  }
  __syncthreads();
  if (tid < N_) degG[tid] = degS[tid];
  if (tid < 64){
    int lane = tid;
    int run = 0;
    for (int c0 = 0; c0 < N_; c0 += 64){
      int n = c0 + lane;
      int v = (n < N_) ? cntS[n] : 0;
      int s = v;
      #pragma unroll
      for (int m = 1; m < 64; m <<= 1){
        int t = __shfl_up(s, m, 64);
        if (lane >= m) s += t;
      }
      int excl = run + s - v;
      if (n < N_){ offs[n] = excl; cursor[n] = excl; }
      run += __shfl(s, 63, 64);
    }
    if (lane == 0) offs[N_] = run;
  }
}

// parallel: blocks 0..47 gnorm + CSR fill + dense-A scatter;
// blocks 48..143 W_gcn/W_gat transpose; blocks 144..383 tconv fragment pack
__global__ void k_gfa(const int* __restrict__ ei, const float* __restrict__ ew,
                      const float* __restrict__ deg, int* __restrict__ cursor,
                      int* __restrict__ csr_soff, float* __restrict__ A32,
                      const float* __restrict__ W_gcn, const float* __restrict__ W_gat,
                      bf* __restrict__ WT, const float* __restrict__ Wt,
                      bf* __restrict__ WB){
  int b = blockIdx.x;
  if (b < 48){
    int e = b * 256 + threadIdx.x;
    if (e >= E2_) return;
    int s = (e < E_) ? ei[e] : (e - E_);
    int d = (e < E_) ? ei[E_ + e] : (e - E_);
    float w = (e < E_) ? ew[e] : 1.0f;
    float ds = deg[s] > 0.f ? rsqrtf(deg[s]) : 0.f;
    float dd = deg[d] > 0.f ? rsqrtf(deg[d]) : 0.f;
    float gn = ds * w * dd;
    int pos = atomicAdd(&cursor[d], 1);
    csr_soff[pos] = s << 13;            // s*8192
    atomicAdd(&A32[d * NP_ + s], gn);
  } else if (b < 144){
    int i = (b - 48) * 256 + threadIdx.x;   // 24576 exact
    int ci = i & 63;
    int co = (i >> 6) & 63;
    int m  = (i >> 12) & 1;
    int l  = i >> 13;
    const float* W = m ? W_gat : W_gcn;
    WT[i] = __float2bfloat16(W[(size_t)(l * 64 + ci) * 64 + co]);
  } else {
    int i = (b - 144) * 256 + threadIdx.x;  // 61440 exact
    int j = i & 7;
    int r = i >> 3;
    int lane = r & 63;
    int mi = (r >> 6) & 3;
    int t2 = r >> 8;            // l*10 + kk
    int kk = t2 % 10, l = t2 / 10;
    int ho = mi * 16 + (lane & 15);
    int k  = kk >> 1;
    int ci = (kk & 1) * 32 + (lane >> 4) * 8 + j;
    WB[i] = __float2bfloat16(Wt[((l * 64 + ho) * 64 + ci) * 5 + k]);
  }
}

// A32 -> A16 bf16 convert (runs after k_gfa completes the scatter)
__global__ void k_acvt(const float* __restrict__ A32, bf* __restrict__ A16){
  int i = blockIdx.x * 256 + threadIdx.x;   // 36864 exact -> 144 blocks
  float4 v = *(const float4*)&A32[i * 4];
  store_bf4(&A16[i * 4], v);
}

// Fused dense GCN + GAT transform (MFMA), 512-thread / 8-wave blocks:
// wave w = (rg = w>>1 rows, nh = w&1 col-half). Same 44KB LDS -> 3 blk/CU
// -> 24 waves/CU (vs 12 at 256 threads): 2x latency hiding. W fragments
// loaded transiently from L2-hot WT (keeps VGPR under the 6-wave/SIMD cap).
__global__ __launch_bounds__(512, 6) void k_gcn_dense(const float* __restrict__ hin,
    const bf* __restrict__ hin16, const bf* __restrict__ A16,
    const bf* __restrict__ WT, const float* __restrict__ b_gcn,
    const float* __restrict__ att_s, const float* __restrict__ att_d,
    bf* __restrict__ gh16, float* __restrict__ asrc, float* __restrict__ adst){
  __shared__ bf As[64 * 136];
  __shared__ bf Bs[64 * 136];
  __shared__ bf ts[64 * 72];
  int tid = threadIdx.x;
  // bijective XCD swizzle over 768 = 8 xcd * 96 blocks: g = xcd*16 + j/6
  int b0 = blockIdx.x;
  int xcd = b0 & 7, jj6 = b0 >> 3;        // jj6 0..95
  int g = xcd * 16 + jj6 / 6;
  int m0 = (jj6 % 6) * 64;
  int lane = tid & 63, w = tid >> 6;      // w 0..7
  int rg = w >> 1, nh = w & 1;            // row-group, col-half
  int lr = lane & 15, lg = lane >> 4;
  f32x4 acc[2];
  { f32x4 zv = {0.f,0.f,0.f,0.f}; acc[0] = zv; acc[1] = zv; }
  for (int kc = 0; kc < 3; ++kc){
    int u = tid & 15, r = tid >> 4;       // r 0..31
    #pragma unroll
    for (int it = 0; it < 2; ++it){
      int row = it * 32 + r;
      *(uint4*)&As[row * 136 + u * 8] =
          *(const uint4*)&A16[(size_t)(m0 + row) * NP_ + kc * 128 + u * 8];
    }
    if (hin16){
      // Bs[c][nn] from bf16 h16 [g][n][c]: pure bit packing
      #pragma unroll
      for (int it = 0; it < 2; ++it){
        int nn = (it * 32 + r) * 2;
        int n = kc * 128 + nn;
        ushort4 va = (n < N_) ? *(const ushort4*)&hin16[((size_t)g * N_ + n) * 64 + u * 4]
                              : make_ushort4(0, 0, 0, 0);
        ushort4 vb = (n + 1 < N_) ? *(const ushort4*)&hin16[((size_t)g * N_ + n + 1) * 64 + u * 4]
                                  : make_ushort4(0, 0, 0, 0);
        unsigned wa[4] = {(unsigned)va.x | ((unsigned)vb.x << 16),
                          (unsigned)va.y | ((unsigned)vb.y << 16),
                          (unsigned)va.z | ((unsigned)vb.z << 16),
                          (unsigned)va.w | ((unsigned)vb.w << 16)};
        #pragma unroll
        for (int q = 0; q < 4; ++q)
          *(unsigned*)&Bs[(u * 4 + q) * 136 + nn] = wa[q];
      }
    } else {
      // Bs[c][nn] via paired-nn transpose from fp32 x [g][n][c] (layer 0)
      #pragma unroll
      for (int it = 0; it < 2; ++it){
        int nn = (it * 32 + r) * 2;
        int n = kc * 128 + nn;
        float4 v0 = (n < N_) ? *(const float4*)&hin[((size_t)g * N_ + n) * 64 + u * 4]
                             : make_float4(0.f, 0.f, 0.f, 0.f);
        float4 v1 = (n + 1 < N_) ? *(const float4*)&hin[((size_t)g * N_ + n + 1) * 64 + u * 4]
                                 : make_float4(0.f, 0.f, 0.f, 0.f);
        float a0[4] = {v0.x, v0.y, v0.z, v0.w};
        float a1[4] = {v1.x, v1.y, v1.z, v1.w};
        #pragma unroll
        for (int q = 0; q < 4; ++q)
          *(unsigned*)&Bs[(u * 4 + q) * 136 + nn] = pk_bf2(a0[q], a1[q]);
      }
    }
    __syncthreads();
    #pragma unroll
    for (int ks = 0; ks < 4; ++ks){
      short8 af = *(const short8*)&As[(rg * 16 + lr) * 136 + ks * 32 + lg * 8];
      #pragma unroll
      for (int j = 0; j < 2; ++j){
        int nt = nh * 2 + j;
        short8 bfr = *(const short8*)&Bs[(nt * 16 + lr) * 136 + ks * 32 + lg * 8];
        acc[j] = __builtin_amdgcn_mfma_f32_16x16x32_bf16(af, bfr, acc[j], 0, 0, 0);
      }
    }
    __syncthreads();
  }
  // tmp -> ts (wave writes its (rg rows, nh col-half)); GEMM2 reads all cols
  #pragma unroll
  for (int j = 0; j < 2; ++j){
    int nt = nh * 2 + j;
    #pragma unroll
    for (int q = 0; q < 4; ++q)
      ts[(rg * 16 + lg * 4 + q) * 72 + nt * 16 + lr] = __float2bfloat16(acc[j][q]);
  }
  __syncthreads();
  // GEMM2: g = gelu(tmp @ W_gcnT + b); W fragment transient from global
  f32x4 acc2[2];
  { f32x4 zv = {0.f,0.f,0.f,0.f}; acc2[0] = zv; acc2[1] = zv; }
  #pragma unroll
  for (int ks = 0; ks < 2; ++ks){
    short8 af = *(const short8*)&ts[(rg * 16 + lr) * 72 + ks * 32 + lg * 8];
    #pragma unroll
    for (int j = 0; j < 2; ++j){
      int nt = nh * 2 + j;
      short8 wf = *(const short8*)&WT[(size_t)(nt * 16 + lr) * 64 + ks * 32 + lg * 8];
      acc2[j] = __builtin_amdgcn_mfma_f32_16x16x32_bf16(af, wf, acc2[j], 0, 0, 0);
    }
  }
  __syncthreads();          // all GEMM2 ts reads complete before overwrite
  #pragma unroll
  for (int j = 0; j < 2; ++j){
    int nt = nh * 2 + j;
    float bv = b_gcn[nt * 16 + lr];
    #pragma unroll
    for (int q = 0; q < 4; ++q){
      float gv = gelu_f(acc2[j][q] + bv);
      ts[(rg * 16 + lg * 4 + q) * 72 + nt * 16 + lr] = __float2bfloat16(gv);
    }
  }
  __syncthreads();
  // GEMM3: gh = g @ W_gatT
  f32x4 acc3[2];
  { f32x4 zv = {0.f,0.f,0.f,0.f}; acc3[0] = zv; acc3[1] = zv; }
  #pragma unroll
  for (int ks = 0; ks < 2; ++ks){
    short8 af = *(const short8*)&ts[(rg * 16 + lr) * 72 + ks * 32 + lg * 8];
    #pragma unroll
    for (int j = 0; j < 2; ++j){
      int nt = nh * 2 + j;
      short8 wf = *(const short8*)&WT[4096 + (size_t)(nt * 16 + lr) * 64 + ks * 32 + lg * 8];
      acc3[j] = __builtin_amdgcn_mfma_f32_16x16x32_bf16(af, wf, acc3[j], 0, 0, 0);
    }
  }
  #pragma unroll
  for (int j = 0; j < 2; ++j){
    int nt = nh * 2 + j;
    float sa = att_s[nt * 16 + lr];
    float sd = att_d[nt * 16 + lr];
    float ps[4], pd[4];
    #pragma unroll
    for (int q = 0; q < 4; ++q){
      int n = m0 + rg * 16 + lg * 4 + q;
      if (n < N_)
        gh16[((size_t)n * G_ + g) * 64 + nt * 16 + lr] = __float2bfloat16(acc3[j][q]);
      ps[q] = acc3[j][q] * sa;
      pd[q] = acc3[j][q] * sd;
    }
    #pragma unroll
    for (int q = 0; q < 4; ++q){
      ps[q] += __shfl_xor(ps[q], 1, 64); ps[q] += __shfl_xor(ps[q], 2, 64);
      ps[q] += __shfl_xor(ps[q], 4, 64); ps[q] += __shfl_xor(ps[q], 8, 64);
      pd[q] += __shfl_xor(pd[q], 1, 64); pd[q] += __shfl_xor(pd[q], 2, 64);
      pd[q] += __shfl_xor(pd[q], 4, 64); pd[q] += __shfl_xor(pd[q], 8, 64);
    }
    if (lr == 0){
      #pragma unroll
      for (int q = 0; q < 4; ++q){
        int n = m0 + rg * 16 + lg * 4 + q;
        if (n < N_){
          asrc[((size_t)n * G_ + g) * 4 + nt] = ps[q];
          adst[((size_t)n * G_ + g) * 4 + nt] = pd[q];
        }
      }
    }
  }
}

// GAT aggregate, single-pass softmax, XCD-swizzled. Writes fp32 hout AND a
// bf16 mirror h16 (consumed by next layer's gcn_dense B-staging).
__global__ __launch_bounds__(256) void k_gat_agg(const bf* __restrict__ gh,
    const float* __restrict__ asrc, const float* __restrict__ adst,
    const int* __restrict__ csr_soff, const int* __restrict__ offs,
    const float* __restrict__ b_gat, const float* __restrict__ ln_g,
    const float* __restrict__ ln_b, const float* __restrict__ hin,
    float* __restrict__ hout, bf* __restrict__ h16out){
  __shared__ int sS[ECAP];
  // bijective swizzle over 1480 = 8 xcd * 185: gg = xcd>>1, n = j*2 + (xcd&1)
  int b0 = blockIdx.x;
  int gg = (b0 & 7) >> 1;
  int n = (b0 >> 3) * 2 + (b0 & 1);
  int tid = threadIdx.x;
  int o0 = offs[n], o1 = offs[n + 1];
  int deg = o1 - o0;
  int cap = deg < ECAP ? deg : ECAP;
  for (int i = tid; i < cap; i += 256) sS[i] = csr_soff[o0 + i];
  __syncthreads();
  int ql = tid >> 3, c8 = tid & 7;
  int g = gg * 32 + ql;
  int head = c8 >> 1;
  int gh4 = g * 4 + head;
  int toff = gg * 2048 + ql * 64 + c8 * 8;
  float adv = adst[n * 512 + gh4];
  float den = 0.f;
  float a[8];
  #pragma unroll
  for (int j = 0; j < 8; ++j) a[j] = 0.f;
  int p = 0;
  for (; p + 2 <= cap; p += 2){
    int s0 = sS[p], s1 = sS[p+1];
    float w0 = __expf(lrelu(asrc[(s0 >> 4) + gh4] + adv));
    float w1 = __expf(lrelu(asrc[(s1 >> 4) + gh4] + adv));
    den += w0 + w1;
    float v0[8], v1[8];
    load_bf8(gh + s0 + toff, v0);
    load_bf8(gh + s1 + toff, v1);
    #pragma unroll
    for (int j = 0; j < 8; ++j) a[j] += w0 * v0[j] + w1 * v1[j];
  }
  for (; p < cap; ++p){
    int sv = sS[p];
    float w0 = __expf(lrelu(asrc[(sv >> 4) + gh4] + adv));
    den += w0;
    float v[8];
    load_bf8(gh + sv + toff, v);
    #pragma unroll
    for (int j = 0; j < 8; ++j) a[j] += w0 * v[j];
  }
  for (int r = cap; r < deg; ++r){
    int sv = csr_soff[o0 + r];
    float w0 = __expf(lrelu(asrc[(sv >> 4) + gh4] + adv));
    den += w0;
    float v[8];
    load_bf8(gh + sv + toff, v);
    #pragma unroll
    for (int j = 0; j < 8; ++j) a[j] += w0 * v[j];
  }
  float inv = 1.f / den;
  float4 bg0 = *(const float4*)&b_gat[c8 * 8];
  float4 bg1 = *(const float4*)&b_gat[c8 * 8 + 4];
  float bb[8] = {bg0.x, bg0.y, bg0.z, bg0.w, bg1.x, bg1.y, bg1.z, bg1.w};
  size_t hbase = ((size_t)g * N_ + n) * 64 + c8 * 8;
  float4 h0 = *(const float4*)&hin[hbase];
  float4 h1 = *(const float4*)&hin[hbase + 4];
  float hh[8] = {h0.x, h0.y, h0.z, h0.w, h1.x, h1.y, h1.z, h1.w};
  float r8[8];
  float s1 = 0.f;
  #pragma unroll
  for (int j = 0; j < 8; ++j){
    r8[j] = a[j] * inv + bb[j] + hh[j];
    s1 += r8[j];
  }
  s1 += __shfl_xor(s1, 1, 64); s1 += __shfl_xor(s1, 2, 64); s1 += __shfl_xor(s1, 4, 64);
  float mu = s1 * (1.f / 64.f);
  float s2 = 0.f;
  #pragma unroll
  for (int j = 0; j < 8; ++j){
    float d = r8[j] - mu;
    s2 += d * d;
  }
  s2 += __shfl_xor(s2, 1, 64); s2 += __shfl_xor(s2, 2, 64); s2 += __shfl_xor(s2, 4, 64);
  float rstd = rsqrtf(s2 * (1.f / 64.f) + 1e-5f);
  float4 lg0 = *(const float4*)&ln_g[c8 * 8];
  float4 lg1 = *(const float4*)&ln_g[c8 * 8 + 4];
  float4 lb0 = *(const float4*)&ln_b[c8 * 8];
  float4 lb1 = *(const float4*)&ln_b[c8 * 8 + 4];
  float lg[8] = {lg0.x, lg0.y, lg0.z, lg0.w, lg1.x, lg1.y, lg1.z, lg1.w};
  float lb[8] = {lb0.x, lb0.y, lb0.z, lb0.w, lb1.x, lb1.y, lb1.z, lb1.w};
  float4 w0v, w1v;
  w0v.x = (r8[0]-mu)*rstd*lg[0]+lb[0]; w0v.y = (r8[1]-mu)*rstd*lg[1]+lb[1];
  w0v.z = (r8[2]-mu)*rstd*lg[2]+lb[2]; w0v.w = (r8[3]-mu)*rstd*lg[3]+lb[3];
  w1v.x = (r8[4]-mu)*rstd*lg[4]+lb[4]; w1v.y = (r8[5]-mu)*rstd*lg[5]+lb[5];
  w1v.z = (r8[6]-mu)*rstd*lg[6]+lb[6]; w1v.w = (r8[7]-mu)*rstd*lg[7]+lb[7];
  *(float4*)&hout[hbase] = w0v;
  *(float4*)&hout[hbase + 4] = w1v;
  bf hv[8] = {__float2bfloat16(w0v.x), __float2bfloat16(w0v.y),
              __float2bfloat16(w0v.z), __float2bfloat16(w0v.w),
              __float2bfloat16(w1v.x), __float2bfloat16(w1v.y),
              __float2bfloat16(w1v.z), __float2bfloat16(w1v.w)};
  *(uint4*)&h16out[hbase] = *(const uint4*)hv;
}

// MFMA temporal conv, 4-wave split per (b,n); wave w owns ho quadrant mi=w.
__global__ __launch_bounds__(256) void k_tfuse(const float* __restrict__ h,
    const bf* __restrict__ WB, const float* __restrict__ bt,
    bf* __restrict__ z16){
  __shared__ float xf[32 * 68];        // fp32 x, [t][ho], pad 68 (residual)
  __shared__ float4 xTgv[36 * 8];      // bf16 x^T, [row=t+2][ci], 128B rows, XOR-swz
  char* xTg = (char*)xTgv;
  int tid = threadIdx.x;
  int w = tid >> 6, lane = tid & 63;
  int bn = blockIdx.x;
  int b = bn / N_, n = bn - b * N_;
  int lq = lane >> 4, lr = lane & 15;
  #pragma unroll
  for (int r = 0; r < 2; ++r){
    int t = w * 8 + r * 4 + lq;
    int c4 = lr * 4;
    float4 v = *(const float4*)&h[((size_t)(b * T_ + t) * N_ + n) * 64 + c4];
    *(float4*)&xf[t * 68 + c4] = v;
    int row = t + 2;
    bf bv[4] = {__float2bfloat16(v.x), __float2bfloat16(v.y),
                __float2bfloat16(v.z), __float2bfloat16(v.w)};
    int bo = (c4 * 2) ^ ((row & 7) << 4);
    *(uint2*)&xTg[row * 128 + bo] = *(const uint2*)bv;
  }
  if (w == 0){           // zero guard rows 0,1,34,35
    int zr = (lq < 2) ? lq : (lq + 32);
    *(uint2*)&xTg[zr * 128 + lr * 8] = make_uint2(0u, 0u);
  }
  __syncthreads();
  for (int l = 0; l < 3; ++l){
    const short8* Wp = (const short8*)(WB + (size_t)l * 20480);
    f32x4 acc[2];
    {
      f32x4 zv = {0.f, 0.f, 0.f, 0.f};
      acc[0] = zv; acc[1] = zv;
    }
    #pragma unroll 2
    for (int kk = 0; kk < 10; ++kk){
      int k = kk >> 1;
      int bbyte = (kk & 1) * 64 + lq * 16;
      short8 bfr[2];
      #pragma unroll
      for (int nj = 0; nj < 2; ++nj){
        int row = nj * 16 + lr + k;
        bfr[nj] = *(const short8*)&xTg[row * 128 + (bbyte ^ ((row & 7) << 4))];
      }
      short8 afr = Wp[(kk * 4 + w) * 64 + lane];
      #pragma unroll
      for (int nj = 0; nj < 2; ++nj)
        acc[nj] = __builtin_amdgcn_mfma_f32_16x16x32_bf16(
            afr, bfr[nj], acc[nj], 0, 0, 0);
    }
    __syncthreads();
    {
      int ho0 = w * 16 + lq * 4;
      float4 bt4 = *(const float4*)&bt[l * 64 + ho0];
      float btv[4] = {bt4.x, bt4.y, bt4.z, bt4.w};
      #pragma unroll
      for (int nj = 0; nj < 2; ++nj){
        int t = nj * 16 + lr;
        float4 xr = *(const float4*)&xf[t * 68 + ho0];
        float xv[4] = {xr.x, xr.y, xr.z, xr.w};
        float ov[4];
        #pragma unroll
        for (int q = 0; q < 4; ++q)
          ov[q] = gelu_f(acc[nj][q] + btv[q]) + xv[q];
        *(float4*)&xf[t * 68 + ho0] = make_float4(ov[0], ov[1], ov[2], ov[3]);
        int row = t + 2;
        bf bvv[4] = {__float2bfloat16(ov[0]), __float2bfloat16(ov[1]),
                     __float2bfloat16(ov[2]), __float2bfloat16(ov[3])};
        *(uint2*)&xTg[row * 128 + ((ho0 * 2) ^ ((row & 7) << 4))] = *(const uint2*)bvv;
      }
    }
    __syncthreads();
  }
  #pragma unroll
  for (int r = 0; r < 2; ++r){
    int t = w * 8 + r * 4 + lq;
    int c4 = lr * 4;
    float4 v = *(const float4*)&xf[t * 68 + c4];
    store_bf4(&z16[(size_t)(b * T_ + t) * NH_ + n * 64 + c4], v);
  }
}

// MFMA MLP layer 1, W1 read DIRECTLY as fp32 (transposed+bf16-packed during
// LDS staging).
__global__ __launch_bounds__(256) void k_mlp1(const bf* __restrict__ z16,
    const float* __restrict__ W1, float* __restrict__ pbuf){
  __shared__ bf zs[128 * 136];
  __shared__ bf ws[128 * 136];
  int kc = blockIdx.x;              // 0..184
  int ch = blockIdx.y;              // 0..1
  int tid = threadIdx.x;
  int k0 = kc * KCH_;
  {
    int u = tid & 15, r = tid >> 4;
    #pragma unroll
    for (int it = 0; it < 8; ++it){
      int row = it * 16 + r;
      uint4 v = *(const uint4*)&z16[(size_t)row * NH_ + k0 + u * 8];
      *(uint4*)&zs[row * 136 + u * 8] = v;
    }
    // ws[col][k] from W1[k][ch*128+col]: k-pairs packed via pk_bf2
    #pragma unroll
    for (int it = 0; it < 4; ++it){
      int kp = it * 16 + r;                 // k-pair index 0..63
      const float* w0p = &W1[(size_t)(k0 + kp * 2) * 256 + ch * 128 + u * 8];
      const float* w1p = w0p + 256;
      float4 wa0 = *(const float4*)w0p, wa1 = *(const float4*)(w0p + 4);
      float4 wb0 = *(const float4*)w1p, wb1 = *(const float4*)(w1p + 4);
      float ca[8] = {wa0.x, wa0.y, wa0.z, wa0.w, wa1.x, wa1.y, wa1.z, wa1.w};
      float cb[8] = {wb0.x, wb0.y, wb0.z, wb0.w, wb1.x, wb1.y, wb1.z, wb1.w};
      #pragma unroll
      for (int q = 0; q < 8; ++q){
        int col = u * 8 + q;
        *(unsigned*)&ws[col * 136 + kp * 2] = pk_bf2(ca[q], cb[q]);
      }
    }
  }
  __syncthreads();
  int lane = tid & 63, w = tid >> 6;
  int lr = lane & 15, lg = lane >> 4;
  int wr = w * 32;
  f32x4 acc[2][8];
  #pragma unroll
  for (int mt = 0; mt < 2; ++mt)
    #pragma unroll
    for (int nt = 0; nt < 8; ++nt){
      f32x4 zv = {0.f, 0.f, 0.f, 0.f};
      acc[mt][nt] = zv;
    }
  #pragma unroll
  for (int ks = 0; ks < 4; ++ks){
    short8 af[2], bfr[8];
    #pragma unroll
    for (int mt = 0; mt < 2; ++mt)
      af[mt] = *(const short8*)&zs[(wr + mt * 16 + lr) * 136 + ks * 32 + lg * 8];
    #pragma unroll
    for (int nt = 0; nt < 8; ++nt)
      bfr[nt] = *(const short8*)&ws[(nt * 16 + lr) * 136 + ks * 32 + lg * 8];
    #pragma unroll
    for (int mt = 0; mt < 2; ++mt)
      #pragma unroll
      for (int nt = 0; nt < 8; ++nt)
        acc[mt][nt] = __builtin_amdgcn_mfma_f32_16x16x32_bf16(
            af[mt], bfr[nt], acc[mt][nt], 0, 0, 0);
  }
  float* pb = pbuf + (size_t)kc * 32768 + ch * 128;
  #pragma unroll
  for (int mt = 0; mt < 2; ++mt)
    #pragma unroll
    for (int nt = 0; nt < 8; ++nt){
      int row = wr + mt * 16 + lg * 4;
      int col = nt * 16 + lr;
      #pragma unroll
      for (int q = 0; q < 4; ++q)
        pb[(size_t)(row + q) * 256 + col] = acc[mt][nt][q];
    }
}

// MLP layer 2, 4-wave version: 1 channel/thread reduction + split GEMM
__global__ __launch_bounds__(256) void k_mlp2(const float* __restrict__ pbuf,
    const float* __restrict__ b1, const float* __restrict__ W2,
    const float* __restrict__ b2, float* __restrict__ outp){
  __shared__ float a[256];
  __shared__ float red[4][64];
  int row = blockIdx.x, tid = threadIdx.x;
  const float* p = pbuf + (size_t)row * 256 + tid;
  float s0 = 0.f, s1 = 0.f, s2 = 0.f, s3 = 0.f, s4 = 0.f;
  for (int kc = 0; kc < NCH_; kc += 5){
    s0 += p[(size_t)(kc+0) * 32768];
    s1 += p[(size_t)(kc+1) * 32768];
    s2 += p[(size_t)(kc+2) * 32768];
    s3 += p[(size_t)(kc+3) * 32768];
    s4 += p[(size_t)(kc+4) * 32768];
  }
  a[tid] = gelu_f(((s0 + s1) + (s2 + s3)) + s4 + b1[tid]);
  __syncthreads();
  int w = tid >> 6, lane = tid & 63;
  float acc = 0.f;
  #pragma unroll
  for (int i = 0; i < 64; ++i)
    acc += a[w * 64 + i] * W2[(w * 64 + i) * 64 + lane];
  red[w][lane] = acc;
  __syncthreads();
  if (tid < 64)
    outp[row * 64 + tid] = red[0][tid] + red[1][tid] + red[2][tid] + red[3][tid]
                           + b2[tid];
}

extern "C" void kernel_launch(void* const* d_in, const int* in_sizes, int n_in,
                              void* d_out, int out_size, void* d_ws, size_t ws_size,
                              hipStream_t stream){
  const float* x     = (const float*)d_in[0];
  const int*   ei    = (const int*)  d_in[1];
  const float* ew    = (const float*)d_in[2];
  const float* W_gcn = (const float*)d_in[3];
  const float* b_gcn = (const float*)d_in[4];
  const float* W_gat = (const float*)d_in[5];
  const float* att_s = (const float*)d_in[6];
  const float* att_d = (const float*)d_in[7];
  const float* b_gat = (const float*)d_in[8];
  const float* W_t   = (const float*)d_in[9];
  const float* b_t   = (const float*)d_in[10];
  const float* ln_g  = (const float*)d_in[11];
  const float* ln_b  = (const float*)d_in[12];
  const float* W1    = (const float*)d_in[13];
  const float* b1    = (const float*)d_in[14];
  const float* W2    = (const float*)d_in[15];
  const float* b2    = (const float*)d_in[16];
  float* outp = (float*)d_out;

  float* F = (float*)d_ws;
  size_t off = 0;
  float* asrc   = F + off; off += 189440;
  float* adst   = F + off; off += 189440;
  float* degG   = F + off; off += 512;
  float* WTf    = F + off; off += 61440;
  float* h      = F + off; off += 3031040;
  float* bufC   = F + off; off += 3031040;   // A32 (fp32) + A16 (bf16)
  float* bufD   = F + off; off += 3031040;   // gh16 (bf16) / z16 (bf16)
  float* bufE   = F + off; off += 1515520;   // h16 (bf16 mirror of h)
  float* pbuf   = F + off; off += (size_t)NCH_ * 32768;
  int* I        = (int*)(F + off);
  int* offs     = I;
  int* cursor   = I + 512;
  int* csr_soff = I + 1024;                  // E2_ entries

  bf* WB     = (bf*)WTf;                     // 61440 bf16 = 30720 floats
  bf* WTT    = (bf*)(WTf + 30720);           // 24576 bf16 (W_gcnT/W_gatT)
  float* A32 = bufC;                         // [384][384] fp32
  bf* A16    = (bf*)(bufC + 147456);         // [384][384] bf16
  bf* gh16   = (bf*)bufD;
  bf* z16    = (bf*)bufD;
  bf* h16    = (bf*)bufE;

  hipMemsetAsync(A32, 0, (size_t)NP_ * NP_ * sizeof(float), stream);

  k_degscan<<<1, 1024, 0, stream>>>(ei, ew, degG, offs, cursor);
  k_gfa<<<384, 256, 0, stream>>>(ei, ew, degG, cursor, csr_soff, A32,
                                 W_gcn, W_gat, WTT, W_t, WB);
  k_acvt<<<144, 256, 0, stream>>>(A32, A16);

  for (int l = 0; l < 3; ++l){
    const float* hin = (l == 0) ? x : h;
    const bf* hin16 = (l == 0) ? (const bf*)nullptr : h16;
    k_gcn_dense<<<768, 512, 0, stream>>>(hin, hin16, A16, WTT + (size_t)l * 8192,
                                         b_gcn + l * 64, att_s + l * 64, att_d + l * 64,
                                         gh16, asrc, adst);
    k_gat_agg<<<1480, 256, 0, stream>>>(gh16, asrc, adst, csr_soff, offs,
                                        b_gat + l * 64, ln_g + l * 64, ln_b + l * 64,
                                        hin, h, h16);
  }

  k_tfuse<<<BN_, 256, 0, stream>>>(h, WB, b_t, z16);

  dim3 g1(NCH_, 2);
  k_mlp1<<<g1, 256, 0, stream>>>(z16, W1, pbuf);
  k_mlp2<<<128, 256, 0, stream>>>(pbuf, b1, W2, b2, outp);
}

// Round 13
// 290.349 us; speedup vs baseline: 1.0230x; 1.0230x over previous
//
#include <hip/hip_runtime.h>
#include <hip/hip_bf16.h>

// Problem constants
#define B_   4
#define T_   32
#define N_   370
#define NP_  384            // N_ padded to 384 for dense-A MFMA
#define E_   11840
#define E2_  12210          // E_ + N_ self loops
#define H_   64
#define G_   128            // B_*T_
#define GN_  47360          // G_*N_
#define BN_  1480           // B_*N_
#define NH_  23680          // N_*H_
#define ECAP 320            // LDS edge-stage capacity per node (max deg ~70)
#define KCH_ 128            // mlp1 MFMA k-chunk (23680 = 128*185)
#define NCH_ 185            // number of k-chunks

typedef __hip_bfloat16 bf;
typedef short short8 __attribute__((ext_vector_type(8)));
typedef float f32x4 __attribute__((ext_vector_type(4)));

__device__ __forceinline__ float gelu_f(float x){
  return 0.5f * x * (1.0f + erff(x * 0.7071067811865475f));
}
__device__ __forceinline__ float lrelu(float v){ return v > 0.f ? v : 0.2f * v; }
__device__ __forceinline__ float b2f(bf x){ return __bfloat162float(x); }
__device__ __forceinline__ void store_bf4(bf* p, float4 v){
  bf tmp[4] = {__float2bfloat16(v.x), __float2bfloat16(v.y),
               __float2bfloat16(v.z), __float2bfloat16(v.w)};
  *(ushort4*)p = *(const ushort4*)tmp;
}
__device__ __forceinline__ unsigned pk_bf2(float a, float b){
  bf lo = __float2bfloat16(a), hi = __float2bfloat16(b);
  return (unsigned)*(unsigned short*)&lo | ((unsigned)*(unsigned short*)&hi << 16);
}
// load 8 consecutive bf16 (16B aligned) -> 8 floats
__device__ __forceinline__ void load_bf8(const bf* p, float* v){
  uint4 u = *(const uint4*)p;
  unsigned ua[4] = {u.x, u.y, u.z, u.w};
  #pragma unroll
  for (int i = 0; i < 4; ++i){
    v[2*i]   = __uint_as_float(ua[i] << 16);
    v[2*i+1] = __uint_as_float(ua[i] & 0xffff0000u);
  }
}

// ---------- edge preprocessing ----------
// single block: deg/count LDS atomics + exclusive scan
__global__ __launch_bounds__(1024) void k_degscan(const int* __restrict__ ei,
    const float* __restrict__ ew, float* __restrict__ degG,
    int* __restrict__ offs, int* __restrict__ cursor){
  __shared__ float degS[512];
  __shared__ int cntS[512];
  int tid = threadIdx.x;
  if (tid < 512){ degS[tid] = 0.f; cntS[tid] = 0; }
  __syncthreads();
  for (int e = tid; e < E2_; e += 1024){
    int dst = (e < E_) ? ei[E_ + e] : (e - E_);
    float w = (e < E_) ? ew[e] : 1.0f;
    atomicAdd(&degS[dst], w);
    atomicAdd(&cntS[dst], 1);
  }
  __syncthreads();
  if (tid < N_) degG[tid] = degS[tid];
  if (tid < 64){
    int lane = tid;
    int run = 0;
    for (int c0 = 0; c0 < N_; c0 += 64){
      int n = c0 + lane;
      int v = (n < N_) ? cntS[n] : 0;
      int s = v;
      #pragma unroll
      for (int m = 1; m < 64; m <<= 1){
        int t = __shfl_up(s, m, 64);
        if (lane >= m) s += t;
      }
      int excl = run + s - v;
      if (n < N_){ offs[n] = excl; cursor[n] = excl; }
      run += __shfl(s, 63, 64);
    }
    if (lane == 0) offs[N_] = run;
  }
}

// parallel: blocks 0..47 gnorm + CSR fill + dense-A scatter;
// blocks 48..143 W_gcn/W_gat transpose; blocks 144..383 tconv fragment pack
__global__ void k_gfa(const int* __restrict__ ei, const float* __restrict__ ew,
                      const float* __restrict__ deg, int* __restrict__ cursor,
                      int* __restrict__ csr_soff, float* __restrict__ A32,
                      const float* __restrict__ W_gcn, const float* __restrict__ W_gat,
                      bf* __restrict__ WT, const float* __restrict__ Wt,
                      bf* __restrict__ WB){
  int b = blockIdx.x;
  if (b < 48){
    int e = b * 256 + threadIdx.x;
    if (e >= E2_) return;
    int s = (e < E_) ? ei[e] : (e - E_);
    int d = (e < E_) ? ei[E_ + e] : (e - E_);
    float w = (e < E_) ? ew[e] : 1.0f;
    float ds = deg[s] > 0.f ? rsqrtf(deg[s]) : 0.f;
    float dd = deg[d] > 0.f ? rsqrtf(deg[d]) : 0.f;
    float gn = ds * w * dd;
    int pos = atomicAdd(&cursor[d], 1);
    csr_soff[pos] = s << 13;            // s*8192
    atomicAdd(&A32[d * NP_ + s], gn);
  } else if (b < 144){
    int i = (b - 48) * 256 + threadIdx.x;   // 24576 exact
    int ci = i & 63;
    int co = (i >> 6) & 63;
    int m  = (i >> 12) & 1;
    int l  = i >> 13;
    const float* W = m ? W_gat : W_gcn;
    WT[i] = __float2bfloat16(W[(size_t)(l * 64 + ci) * 64 + co]);
  } else {
    int i = (b - 144) * 256 + threadIdx.x;  // 61440 exact
    int j = i & 7;
    int r = i >> 3;
    int lane = r & 63;
    int mi = (r >> 6) & 3;
    int t2 = r >> 8;            // l*10 + kk
    int kk = t2 % 10, l = t2 / 10;
    int ho = mi * 16 + (lane & 15);
    int k  = kk >> 1;
    int ci = (kk & 1) * 32 + (lane >> 4) * 8 + j;
    WB[i] = __float2bfloat16(Wt[((l * 64 + ho) * 64 + ci) * 5 + k]);
  }
}

// A32 -> A16 bf16 convert (runs after k_gfa completes the scatter)
__global__ void k_acvt(const float* __restrict__ A32, bf* __restrict__ A16){
  int i = blockIdx.x * 256 + threadIdx.x;   // 36864 exact -> 144 blocks
  float4 v = *(const float4*)&A32[i * 4];
  store_bf4(&A16[i * 4], v);
}

// Fused dense GCN + GAT transform (MFMA), 512-thread / 8-wave blocks:
// wave w = (rg = w>>1 rows, nh = w&1 col-half). 44KB LDS -> 3 blk/CU ->
// 24 waves/CU. W fragments loaded transiently from L2-hot WT.
__global__ __launch_bounds__(512, 6) void k_gcn_dense(const float* __restrict__ hin,
    const bf* __restrict__ hin16, const bf* __restrict__ A16,
    const bf* __restrict__ WT, const float* __restrict__ b_gcn,
    const float* __restrict__ att_s, const float* __restrict__ att_d,
    bf* __restrict__ gh16, float* __restrict__ asrc, float* __restrict__ adst){
  __shared__ bf As[64 * 136];
  __shared__ bf Bs[64 * 136];
  __shared__ bf ts[64 * 72];
  int tid = threadIdx.x;
  // bijective XCD swizzle over 768 = 8 xcd * 96 blocks: g = xcd*16 + j/6
  int b0 = blockIdx.x;
  int xcd = b0 & 7, jj6 = b0 >> 3;        // jj6 0..95
  int g = xcd * 16 + jj6 / 6;
  int m0 = (jj6 % 6) * 64;
  int lane = tid & 63, w = tid >> 6;      // w 0..7
  int rg = w >> 1, nh = w & 1;            // row-group, col-half
  int lr = lane & 15, lg = lane >> 4;
  f32x4 acc[2];
  { f32x4 zv = {0.f,0.f,0.f,0.f}; acc[0] = zv; acc[1] = zv; }
  for (int kc = 0; kc < 3; ++kc){
    int u = tid & 15, r = tid >> 4;       // r 0..31
    #pragma unroll
    for (int it = 0; it < 2; ++it){
      int row = it * 32 + r;
      *(uint4*)&As[row * 136 + u * 8] =
          *(const uint4*)&A16[(size_t)(m0 + row) * NP_ + kc * 128 + u * 8];
    }
    if (hin16){
      #pragma unroll
      for (int it = 0; it < 2; ++it){
        int nn = (it * 32 + r) * 2;
        int n = kc * 128 + nn;
        ushort4 va = (n < N_) ? *(const ushort4*)&hin16[((size_t)g * N_ + n) * 64 + u * 4]
                              : make_ushort4(0, 0, 0, 0);
        ushort4 vb = (n + 1 < N_) ? *(const ushort4*)&hin16[((size_t)g * N_ + n + 1) * 64 + u * 4]
                                  : make_ushort4(0, 0, 0, 0);
        unsigned wa[4] = {(unsigned)va.x | ((unsigned)vb.x << 16),
                          (unsigned)va.y | ((unsigned)vb.y << 16),
                          (unsigned)va.z | ((unsigned)vb.z << 16),
                          (unsigned)va.w | ((unsigned)vb.w << 16)};
        #pragma unroll
        for (int q = 0; q < 4; ++q)
          *(unsigned*)&Bs[(u * 4 + q) * 136 + nn] = wa[q];
      }
    } else {
      #pragma unroll
      for (int it = 0; it < 2; ++it){
        int nn = (it * 32 + r) * 2;
        int n = kc * 128 + nn;
        float4 v0 = (n < N_) ? *(const float4*)&hin[((size_t)g * N_ + n) * 64 + u * 4]
                             : make_float4(0.f, 0.f, 0.f, 0.f);
        float4 v1 = (n + 1 < N_) ? *(const float4*)&hin[((size_t)g * N_ + n + 1) * 64 + u * 4]
                                 : make_float4(0.f, 0.f, 0.f, 0.f);
        float a0[4] = {v0.x, v0.y, v0.z, v0.w};
        float a1[4] = {v1.x, v1.y, v1.z, v1.w};
        #pragma unroll
        for (int q = 0; q < 4; ++q)
          *(unsigned*)&Bs[(u * 4 + q) * 136 + nn] = pk_bf2(a0[q], a1[q]);
      }
    }
    __syncthreads();
    #pragma unroll
    for (int ks = 0; ks < 4; ++ks){
      short8 af = *(const short8*)&As[(rg * 16 + lr) * 136 + ks * 32 + lg * 8];
      #pragma unroll
      for (int j = 0; j < 2; ++j){
        int nt = nh * 2 + j;
        short8 bfr = *(const short8*)&Bs[(nt * 16 + lr) * 136 + ks * 32 + lg * 8];
        acc[j] = __builtin_amdgcn_mfma_f32_16x16x32_bf16(af, bfr, acc[j], 0, 0, 0);
      }
    }
    __syncthreads();
  }
  #pragma unroll
  for (int j = 0; j < 2; ++j){
    int nt = nh * 2 + j;
    #pragma unroll
    for (int q = 0; q < 4; ++q)
      ts[(rg * 16 + lg * 4 + q) * 72 + nt * 16 + lr] = __float2bfloat16(acc[j][q]);
  }
  __syncthreads();
  f32x4 acc2[2];
  { f32x4 zv = {0.f,0.f,0.f,0.f}; acc2[0] = zv; acc2[1] = zv; }
  #pragma unroll
  for (int ks = 0; ks < 2; ++ks){
    short8 af = *(const short8*)&ts[(rg * 16 + lr) * 72 + ks * 32 + lg * 8];
    #pragma unroll
    for (int j = 0; j < 2; ++j){
      int nt = nh * 2 + j;
      short8 wf = *(const short8*)&WT[(size_t)(nt * 16 + lr) * 64 + ks * 32 + lg * 8];
      acc2[j] = __builtin_amdgcn_mfma_f32_16x16x32_bf16(af, wf, acc2[j], 0, 0, 0);
    }
  }
  __syncthreads();
  #pragma unroll
  for (int j = 0; j < 2; ++j){
    int nt = nh * 2 + j;
    float bv = b_gcn[nt * 16 + lr];
    #pragma unroll
    for (int q = 0; q < 4; ++q){
      float gv = gelu_f(acc2[j][q] + bv);
      ts[(rg * 16 + lg * 4 + q) * 72 + nt * 16 + lr] = __float2bfloat16(gv);
    }
  }
  __syncthreads();
  f32x4 acc3[2];
  { f32x4 zv = {0.f,0.f,0.f,0.f}; acc3[0] = zv; acc3[1] = zv; }
  #pragma unroll
  for (int ks = 0; ks < 2; ++ks){
    short8 af = *(const short8*)&ts[(rg * 16 + lr) * 72 + ks * 32 + lg * 8];
    #pragma unroll
    for (int j = 0; j < 2; ++j){
      int nt = nh * 2 + j;
      short8 wf = *(const short8*)&WT[4096 + (size_t)(nt * 16 + lr) * 64 + ks * 32 + lg * 8];
      acc3[j] = __builtin_amdgcn_mfma_f32_16x16x32_bf16(af, wf, acc3[j], 0, 0, 0);
    }
  }
  #pragma unroll
  for (int j = 0; j < 2; ++j){
    int nt = nh * 2 + j;
    float sa = att_s[nt * 16 + lr];
    float sd = att_d[nt * 16 + lr];
    float ps[4], pd[4];
    #pragma unroll
    for (int q = 0; q < 4; ++q){
      int n = m0 + rg * 16 + lg * 4 + q;
      if (n < N_)
        gh16[((size_t)n * G_ + g) * 64 + nt * 16 + lr] = __float2bfloat16(acc3[j][q]);
      ps[q] = acc3[j][q] * sa;
      pd[q] = acc3[j][q] * sd;
    }
    #pragma unroll
    for (int q = 0; q < 4; ++q){
      ps[q] += __shfl_xor(ps[q], 1, 64); ps[q] += __shfl_xor(ps[q], 2, 64);
      ps[q] += __shfl_xor(ps[q], 4, 64); ps[q] += __shfl_xor(ps[q], 8, 64);
      pd[q] += __shfl_xor(pd[q], 1, 64); pd[q] += __shfl_xor(pd[q], 2, 64);
      pd[q] += __shfl_xor(pd[q], 4, 64); pd[q] += __shfl_xor(pd[q], 8, 64);
    }
    if (lr == 0){
      #pragma unroll
      for (int q = 0; q < 4; ++q){
        int n = m0 + rg * 16 + lg * 4 + q;
        if (n < N_){
          asrc[((size_t)n * G_ + g) * 4 + nt] = ps[q];
          adst[((size_t)n * G_ + g) * 4 + nt] = pd[q];
        }
      }
    }
  }
}

// GAT aggregate, single-pass softmax, XCD-swizzled (layers 0,1).
// Writes fp32 hout AND a bf16 mirror h16.
__global__ __launch_bounds__(256) void k_gat_agg(const bf* __restrict__ gh,
    const float* __restrict__ asrc, const float* __restrict__ adst,
    const int* __restrict__ csr_soff, const int* __restrict__ offs,
    const float* __restrict__ b_gat, const float* __restrict__ ln_g,
    const float* __restrict__ ln_b, const float* __restrict__ hin,
    float* __restrict__ hout, bf* __restrict__ h16out){
  __shared__ int sS[ECAP];
  int b0 = blockIdx.x;
  int gg = (b0 & 7) >> 1;
  int n = (b0 >> 3) * 2 + (b0 & 1);
  int tid = threadIdx.x;
  int o0 = offs[n], o1 = offs[n + 1];
  int deg = o1 - o0;
  int cap = deg < ECAP ? deg : ECAP;
  for (int i = tid; i < cap; i += 256) sS[i] = csr_soff[o0 + i];
  __syncthreads();
  int ql = tid >> 3, c8 = tid & 7;
  int g = gg * 32 + ql;
  int head = c8 >> 1;
  int gh4 = g * 4 + head;
  int toff = gg * 2048 + ql * 64 + c8 * 8;
  float adv = adst[n * 512 + gh4];
  float den = 0.f;
  float a[8];
  #pragma unroll
  for (int j = 0; j < 8; ++j) a[j] = 0.f;
  int p = 0;
  for (; p + 2 <= cap; p += 2){
    int s0 = sS[p], s1 = sS[p+1];
    float w0 = __expf(lrelu(asrc[(s0 >> 4) + gh4] + adv));
    float w1 = __expf(lrelu(asrc[(s1 >> 4) + gh4] + adv));
    den += w0 + w1;
    float v0[8], v1[8];
    load_bf8(gh + s0 + toff, v0);
    load_bf8(gh + s1 + toff, v1);
    #pragma unroll
    for (int j = 0; j < 8; ++j) a[j] += w0 * v0[j] + w1 * v1[j];
  }
  for (; p < cap; ++p){
    int sv = sS[p];
    float w0 = __expf(lrelu(asrc[(sv >> 4) + gh4] + adv));
    den += w0;
    float v[8];
    load_bf8(gh + sv + toff, v);
    #pragma unroll
    for (int j = 0; j < 8; ++j) a[j] += w0 * v[j];
  }
  for (int r = cap; r < deg; ++r){
    int sv = csr_soff[o0 + r];
    float w0 = __expf(lrelu(asrc[(sv >> 4) + gh4] + adv));
    den += w0;
    float v[8];
    load_bf8(gh + sv + toff, v);
    #pragma unroll
    for (int j = 0; j < 8; ++j) a[j] += w0 * v[j];
  }
  float inv = 1.f / den;
  float4 bg0 = *(const float4*)&b_gat[c8 * 8];
  float4 bg1 = *(const float4*)&b_gat[c8 * 8 + 4];
  float bb[8] = {bg0.x, bg0.y, bg0.z, bg0.w, bg1.x, bg1.y, bg1.z, bg1.w};
  size_t hbase = ((size_t)g * N_ + n) * 64 + c8 * 8;
  float4 h0 = *(const float4*)&hin[hbase];
  float4 h1 = *(const float4*)&hin[hbase + 4];
  float hh[8] = {h0.x, h0.y, h0.z, h0.w, h1.x, h1.y, h1.z, h1.w};
  float r8[8];
  float s1 = 0.f;
  #pragma unroll
  for (int j = 0; j < 8; ++j){
    r8[j] = a[j] * inv + bb[j] + hh[j];
    s1 += r8[j];
  }
  s1 += __shfl_xor(s1, 1, 64); s1 += __shfl_xor(s1, 2, 64); s1 += __shfl_xor(s1, 4, 64);
  float mu = s1 * (1.f / 64.f);
  float s2 = 0.f;
  #pragma unroll
  for (int j = 0; j < 8; ++j){
    float d = r8[j] - mu;
    s2 += d * d;
  }
  s2 += __shfl_xor(s2, 1, 64); s2 += __shfl_xor(s2, 2, 64); s2 += __shfl_xor(s2, 4, 64);
  float rstd = rsqrtf(s2 * (1.f / 64.f) + 1e-5f);
  float4 lg0 = *(const float4*)&ln_g[c8 * 8];
  float4 lg1 = *(const float4*)&ln_g[c8 * 8 + 4];
  float4 lb0 = *(const float4*)&ln_b[c8 * 8];
  float4 lb1 = *(const float4*)&ln_b[c8 * 8 + 4];
  float lg[8] = {lg0.x, lg0.y, lg0.z, lg0.w, lg1.x, lg1.y, lg1.z, lg1.w};
  float lb[8] = {lb0.x, lb0.y, lb0.z, lb0.w, lb1.x, lb1.y, lb1.z, lb1.w};
  float4 w0v, w1v;
  w0v.x = (r8[0]-mu)*rstd*lg[0]+lb[0]; w0v.y = (r8[1]-mu)*rstd*lg[1]+lb[1];
  w0v.z = (r8[2]-mu)*rstd*lg[2]+lb[2]; w0v.w = (r8[3]-mu)*rstd*lg[3]+lb[3];
  w1v.x = (r8[4]-mu)*rstd*lg[4]+lb[4]; w1v.y = (r8[5]-mu)*rstd*lg[5]+lb[5];
  w1v.z = (r8[6]-mu)*rstd*lg[6]+lb[6]; w1v.w = (r8[7]-mu)*rstd*lg[7]+lb[7];
  *(float4*)&hout[hbase] = w0v;
  *(float4*)&hout[hbase + 4] = w1v;
  bf hv[8] = {__float2bfloat16(w0v.x), __float2bfloat16(w0v.y),
              __float2bfloat16(w0v.z), __float2bfloat16(w0v.w),
              __float2bfloat16(w1v.x), __float2bfloat16(w1v.y),
              __float2bfloat16(w1v.z), __float2bfloat16(w1v.w)};
  *(uint4*)&h16out[hbase] = *(const uint4*)hv;
}

// LAYER-2 FUSION: gat_agg + temporal conv. Block (n, gg) = exactly the
// [32 t][64 c] tile of batch b=gg that tfuse needed: thread (ql=t, c8)
// deposits its LN output into xf/xTg LDS, then the conv runs in-block.
// h / h16 writes and the separate tfuse launch are eliminated.
__global__ __launch_bounds__(256) void k_gat_tfuse(const bf* __restrict__ gh,
    const float* __restrict__ asrc, const float* __restrict__ adst,
    const int* __restrict__ csr_soff, const int* __restrict__ offs,
    const float* __restrict__ b_gat, const float* __restrict__ ln_g,
    const float* __restrict__ ln_b, const float* __restrict__ hin,
    const bf* __restrict__ WB, const float* __restrict__ bt,
    bf* __restrict__ z16){
  __shared__ int sS[ECAP];
  __shared__ float xf[32 * 68];        // fp32 LN-out tile [t][c]
  __shared__ float4 xTgv[36 * 8];      // bf16 x^T, XOR-swz, 2 guard rows each end
  char* xTg = (char*)xTgv;
  int b0 = blockIdx.x;
  int gg = (b0 & 7) >> 1;              // = batch b
  int n = (b0 >> 3) * 2 + (b0 & 1);
  int tid = threadIdx.x;
  int o0 = offs[n], o1 = offs[n + 1];
  int deg = o1 - o0;
  int cap = deg < ECAP ? deg : ECAP;
  for (int i = tid; i < cap; i += 256) sS[i] = csr_soff[o0 + i];
  __syncthreads();
  int ql = tid >> 3, c8 = tid & 7;
  int g = gg * 32 + ql;
  int head = c8 >> 1;
  int gh4 = g * 4 + head;
  int toff = gg * 2048 + ql * 64 + c8 * 8;
  float adv = adst[n * 512 + gh4];
  float den = 0.f;
  float a[8];
  #pragma unroll
  for (int j = 0; j < 8; ++j) a[j] = 0.f;
  int p = 0;
  for (; p + 2 <= cap; p += 2){
    int s0 = sS[p], s1 = sS[p+1];
    float w0 = __expf(lrelu(asrc[(s0 >> 4) + gh4] + adv));
    float w1 = __expf(lrelu(asrc[(s1 >> 4) + gh4] + adv));
    den += w0 + w1;
    float v0[8], v1[8];
    load_bf8(gh + s0 + toff, v0);
    load_bf8(gh + s1 + toff, v1);
    #pragma unroll
    for (int j = 0; j < 8; ++j) a[j] += w0 * v0[j] + w1 * v1[j];
  }
  for (; p < cap; ++p){
    int sv = sS[p];
    float w0 = __expf(lrelu(asrc[(sv >> 4) + gh4] + adv));
    den += w0;
    float v[8];
    load_bf8(gh + sv + toff, v);
    #pragma unroll
    for (int j = 0; j < 8; ++j) a[j] += w0 * v[j];
  }
  for (int r = cap; r < deg; ++r){
    int sv = csr_soff[o0 + r];
    float w0 = __expf(lrelu(asrc[(sv >> 4) + gh4] + adv));
    den += w0;
    float v[8];
    load_bf8(gh + sv + toff, v);
    #pragma unroll
    for (int j = 0; j < 8; ++j) a[j] += w0 * v[j];
  }
  float inv = 1.f / den;
  float4 bg0 = *(const float4*)&b_gat[c8 * 8];
  float4 bg1 = *(const float4*)&b_gat[c8 * 8 + 4];
  float bb[8] = {bg0.x, bg0.y, bg0.z, bg0.w, bg1.x, bg1.y, bg1.z, bg1.w};
  size_t hbase = ((size_t)g * N_ + n) * 64 + c8 * 8;
  float4 h0 = *(const float4*)&hin[hbase];
  float4 h1 = *(const float4*)&hin[hbase + 4];
  float hh[8] = {h0.x, h0.y, h0.z, h0.w, h1.x, h1.y, h1.z, h1.w};
  float r8[8];
  float s1 = 0.f;
  #pragma unroll
  for (int j = 0; j < 8; ++j){
    r8[j] = a[j] * inv + bb[j] + hh[j];
    s1 += r8[j];
  }
  s1 += __shfl_xor(s1, 1, 64); s1 += __shfl_xor(s1, 2, 64); s1 += __shfl_xor(s1, 4, 64);
  float mu = s1 * (1.f / 64.f);
  float s2 = 0.f;
  #pragma unroll
  for (int j = 0; j < 8; ++j){
    float d = r8[j] - mu;
    s2 += d * d;
  }
  s2 += __shfl_xor(s2, 1, 64); s2 += __shfl_xor(s2, 2, 64); s2 += __shfl_xor(s2, 4, 64);
  float rstd = rsqrtf(s2 * (1.f / 64.f) + 1e-5f);
  float4 lg0 = *(const float4*)&ln_g[c8 * 8];
  float4 lg1 = *(const float4*)&ln_g[c8 * 8 + 4];
  float4 lb0 = *(const float4*)&ln_b[c8 * 8];
  float4 lb1 = *(const float4*)&ln_b[c8 * 8 + 4];
  float lg[8] = {lg0.x, lg0.y, lg0.z, lg0.w, lg1.x, lg1.y, lg1.z, lg1.w};
  float lb[8] = {lb0.x, lb0.y, lb0.z, lb0.w, lb1.x, lb1.y, lb1.z, lb1.w};
  float4 w0v, w1v;
  w0v.x = (r8[0]-mu)*rstd*lg[0]+lb[0]; w0v.y = (r8[1]-mu)*rstd*lg[1]+lb[1];
  w0v.z = (r8[2]-mu)*rstd*lg[2]+lb[2]; w0v.w = (r8[3]-mu)*rstd*lg[3]+lb[3];
  w1v.x = (r8[4]-mu)*rstd*lg[4]+lb[4]; w1v.y = (r8[5]-mu)*rstd*lg[5]+lb[5];
  w1v.z = (r8[6]-mu)*rstd*lg[6]+lb[6]; w1v.w = (r8[7]-mu)*rstd*lg[7]+lb[7];
  // deposit LN output into conv tiles (t = ql): fp32 xf + swizzled bf16 xTg
  {
    int t = ql;
    *(float4*)&xf[t * 68 + c8 * 8] = w0v;
    *(float4*)&xf[t * 68 + c8 * 8 + 4] = w1v;
    int row = t + 2;
    bf hv[8] = {__float2bfloat16(w0v.x), __float2bfloat16(w0v.y),
                __float2bfloat16(w0v.z), __float2bfloat16(w0v.w),
                __float2bfloat16(w1v.x), __float2bfloat16(w1v.y),
                __float2bfloat16(w1v.z), __float2bfloat16(w1v.w)};
    int sw = (row & 7) << 4;
    *(uint2*)&xTg[row * 128 + ((c8 * 16) ^ sw)] = *(const uint2*)&hv[0];
    *(uint2*)&xTg[row * 128 + (((c8 * 8 + 4) * 2) ^ sw)] = *(const uint2*)&hv[4];
  }
  if (tid < 64){                       // zero guard rows 0,1,34,35
    int lq0 = tid >> 4, lr0 = tid & 15;
    int zr = (lq0 < 2) ? lq0 : (lq0 + 32);
    *(uint2*)&xTg[zr * 128 + lr0 * 8] = make_uint2(0u, 0u);
  }
  __syncthreads();
  // temporal conv (3 layers), 4-wave split: wave w owns ho quadrant mi=w
  int w = tid >> 6, lane = tid & 63;
  int lq = lane >> 4, lrc = lane & 15;
  for (int l = 0; l < 3; ++l){
    const short8* Wp = (const short8*)(WB + (size_t)l * 20480);
    f32x4 acc[2];
    { f32x4 zv = {0.f, 0.f, 0.f, 0.f}; acc[0] = zv; acc[1] = zv; }
    #pragma unroll 2
    for (int kk = 0; kk < 10; ++kk){
      int k = kk >> 1;
      int bbyte = (kk & 1) * 64 + lq * 16;
      short8 bfr[2];
      #pragma unroll
      for (int nj = 0; nj < 2; ++nj){
        int row = nj * 16 + lrc + k;
        bfr[nj] = *(const short8*)&xTg[row * 128 + (bbyte ^ ((row & 7) << 4))];
      }
      short8 afr = Wp[(kk * 4 + w) * 64 + lane];
      #pragma unroll
      for (int nj = 0; nj < 2; ++nj)
        acc[nj] = __builtin_amdgcn_mfma_f32_16x16x32_bf16(
            afr, bfr[nj], acc[nj], 0, 0, 0);
    }
    __syncthreads();
    {
      int ho0 = w * 16 + lq * 4;
      float4 bt4 = *(const float4*)&bt[l * 64 + ho0];
      float btv[4] = {bt4.x, bt4.y, bt4.z, bt4.w};
      #pragma unroll
      for (int nj = 0; nj < 2; ++nj){
        int t = nj * 16 + lrc;
        float4 xr = *(const float4*)&xf[t * 68 + ho0];
        float xv[4] = {xr.x, xr.y, xr.z, xr.w};
        float ov[4];
        #pragma unroll
        for (int q = 0; q < 4; ++q)
          ov[q] = gelu_f(acc[nj][q] + btv[q]) + xv[q];
        *(float4*)&xf[t * 68 + ho0] = make_float4(ov[0], ov[1], ov[2], ov[3]);
        int row = t + 2;
        bf bvv[4] = {__float2bfloat16(ov[0]), __float2bfloat16(ov[1]),
                     __float2bfloat16(ov[2]), __float2bfloat16(ov[3])};
        *(uint2*)&xTg[row * 128 + ((ho0 * 2) ^ ((row & 7) << 4))] = *(const uint2*)bvv;
      }
    }
    __syncthreads();
  }
  #pragma unroll
  for (int r = 0; r < 2; ++r){
    int t = w * 8 + r * 4 + lq;
    int c4 = lrc * 4;
    float4 v = *(const float4*)&xf[t * 68 + c4];
    store_bf4(&z16[(size_t)(gg * T_ + t) * NH_ + n * 64 + c4], v);
  }
}

// MFMA MLP layer 1, W1 read DIRECTLY as fp32 (transposed+bf16-packed during
// LDS staging).
__global__ __launch_bounds__(256) void k_mlp1(const bf* __restrict__ z16,
    const float* __restrict__ W1, float* __restrict__ pbuf){
  __shared__ bf zs[128 * 136];
  __shared__ bf ws[128 * 136];
  int kc = blockIdx.x;              // 0..184
  int ch = blockIdx.y;              // 0..1
  int tid = threadIdx.x;
  int k0 = kc * KCH_;
  {
    int u = tid & 15, r = tid >> 4;
    #pragma unroll
    for (int it = 0; it < 8; ++it){
      int row = it * 16 + r;
      uint4 v = *(const uint4*)&z16[(size_t)row * NH_ + k0 + u * 8];
      *(uint4*)&zs[row * 136 + u * 8] = v;
    }
    #pragma unroll
    for (int it = 0; it < 4; ++it){
      int kp = it * 16 + r;                 // k-pair index 0..63
      const float* w0p = &W1[(size_t)(k0 + kp * 2) * 256 + ch * 128 + u * 8];
      const float* w1p = w0p + 256;
      float4 wa0 = *(const float4*)w0p, wa1 = *(const float4*)(w0p + 4);
      float4 wb0 = *(const float4*)w1p, wb1 = *(const float4*)(w1p + 4);
      float ca[8] = {wa0.x, wa0.y, wa0.z, wa0.w, wa1.x, wa1.y, wa1.z, wa1.w};
      float cb[8] = {wb0.x, wb0.y, wb0.z, wb0.w, wb1.x, wb1.y, wb1.z, wb1.w};
      #pragma unroll
      for (int q = 0; q < 8; ++q){
        int col = u * 8 + q;
        *(unsigned*)&ws[col * 136 + kp * 2] = pk_bf2(ca[q], cb[q]);
      }
    }
  }
  __syncthreads();
  int lane = tid & 63, w = tid >> 6;
  int lr = lane & 15, lg = lane >> 4;
  int wr = w * 32;
  f32x4 acc[2][8];
  #pragma unroll
  for (int mt = 0; mt < 2; ++mt)
    #pragma unroll
    for (int nt = 0; nt < 8; ++nt){
      f32x4 zv = {0.f, 0.f, 0.f, 0.f};
      acc[mt][nt] = zv;
    }
  #pragma unroll
  for (int ks = 0; ks < 4; ++ks){
    short8 af[2], bfr[8];
    #pragma unroll
    for (int mt = 0; mt < 2; ++mt)
      af[mt] = *(const short8*)&zs[(wr + mt * 16 + lr) * 136 + ks * 32 + lg * 8];
    #pragma unroll
    for (int nt = 0; nt < 8; ++nt)
      bfr[nt] = *(const short8*)&ws[(nt * 16 + lr) * 136 + ks * 32 + lg * 8];
    #pragma unroll
    for (int mt = 0; mt < 2; ++mt)
      #pragma unroll
      for (int nt = 0; nt < 8; ++nt)
        acc[mt][nt] = __builtin_amdgcn_mfma_f32_16x16x32_bf16(
            af[mt], bfr[nt], acc[mt][nt], 0, 0, 0);
  }
  float* pb = pbuf + (size_t)kc * 32768 + ch * 128;
  #pragma unroll
  for (int mt = 0; mt < 2; ++mt)
    #pragma unroll
    for (int nt = 0; nt < 8; ++nt){
      int row = wr + mt * 16 + lg * 4;
      int col = nt * 16 + lr;
      #pragma unroll
      for (int q = 0; q < 4; ++q)
        pb[(size_t)(row + q) * 256 + col] = acc[mt][nt][q];
    }
}

// MLP layer 2, 4-wave version: 1 channel/thread reduction + split GEMM
__global__ __launch_bounds__(256) void k_mlp2(const float* __restrict__ pbuf,
    const float* __restrict__ b1, const float* __restrict__ W2,
    const float* __restrict__ b2, float* __restrict__ outp){
  __shared__ float a[256];
  __shared__ float red[4][64];
  int row = blockIdx.x, tid = threadIdx.x;
  const float* p = pbuf + (size_t)row * 256 + tid;
  float s0 = 0.f, s1 = 0.f, s2 = 0.f, s3 = 0.f, s4 = 0.f;
  for (int kc = 0; kc < NCH_; kc += 5){
    s0 += p[(size_t)(kc+0) * 32768];
    s1 += p[(size_t)(kc+1) * 32768];
    s2 += p[(size_t)(kc+2) * 32768];
    s3 += p[(size_t)(kc+3) * 32768];
    s4 += p[(size_t)(kc+4) * 32768];
  }
  a[tid] = gelu_f(((s0 + s1) + (s2 + s3)) + s4 + b1[tid]);
  __syncthreads();
  int w = tid >> 6, lane = tid & 63;
  float acc = 0.f;
  #pragma unroll
  for (int i = 0; i < 64; ++i)
    acc += a[w * 64 + i] * W2[(w * 64 + i) * 64 + lane];
  red[w][lane] = acc;
  __syncthreads();
  if (tid < 64)
    outp[row * 64 + tid] = red[0][tid] + red[1][tid] + red[2][tid] + red[3][tid]
                           + b2[tid];
}

extern "C" void kernel_launch(void* const* d_in, const int* in_sizes, int n_in,
                              void* d_out, int out_size, void* d_ws, size_t ws_size,
                              hipStream_t stream){
  const float* x     = (const float*)d_in[0];
  const int*   ei    = (const int*)  d_in[1];
  const float* ew    = (const float*)d_in[2];
  const float* W_gcn = (const float*)d_in[3];
  const float* b_gcn = (const float*)d_in[4];
  const float* W_gat = (const float*)d_in[5];
  const float* att_s = (const float*)d_in[6];
  const float* att_d = (const float*)d_in[7];
  const float* b_gat = (const float*)d_in[8];
  const float* W_t   = (const float*)d_in[9];
  const float* b_t   = (const float*)d_in[10];
  const float* ln_g  = (const float*)d_in[11];
  const float* ln_b  = (const float*)d_in[12];
  const float* W1    = (const float*)d_in[13];
  const float* b1    = (const float*)d_in[14];
  const float* W2    = (const float*)d_in[15];
  const float* b2    = (const float*)d_in[16];
  float* outp = (float*)d_out;

  float* F = (float*)d_ws;
  size_t off = 0;
  float* asrc   = F + off; off += 189440;
  float* adst   = F + off; off += 189440;
  float* degG   = F + off; off += 512;
  float* WTf    = F + off; off += 61440;
  float* h      = F + off; off += 3031040;
  float* bufC   = F + off; off += 3031040;   // A32 (fp32) + A16 (bf16)
  float* bufD   = F + off; off += 3031040;   // gh16 (bf16) / z16 (bf16)
  float* bufE   = F + off; off += 1515520;   // h16 (bf16 mirror of h)
  float* pbuf   = F + off; off += (size_t)NCH_ * 32768;
  int* I        = (int*)(F + off);
  int* offs     = I;
  int* cursor   = I + 512;
  int* csr_soff = I + 1024;                  // E2_ entries

  bf* WB     = (bf*)WTf;                     // 61440 bf16 = 30720 floats
  bf* WTT    = (bf*)(WTf + 30720);           // 24576 bf16 (W_gcnT/W_gatT)
  float* A32 = bufC;                         // [384][384] fp32
  bf* A16    = (bf*)(bufC + 147456);         // [384][384] bf16
  bf* gh16   = (bf*)bufD;
  bf* z16    = (bf*)bufE;                    // z16 reuses h16 slot (dead at l=2)
  bf* h16    = (bf*)bufE;

  hipMemsetAsync(A32, 0, (size_t)NP_ * NP_ * sizeof(float), stream);

  k_degscan<<<1, 1024, 0, stream>>>(ei, ew, degG, offs, cursor);
  k_gfa<<<384, 256, 0, stream>>>(ei, ew, degG, cursor, csr_soff, A32,
                                 W_gcn, W_gat, WTT, W_t, WB);
  k_acvt<<<144, 256, 0, stream>>>(A32, A16);

  for (int l = 0; l < 2; ++l){
    const float* hin = (l == 0) ? x : h;
    const bf* hin16 = (l == 0) ? (const bf*)nullptr : h16;
    k_gcn_dense<<<768, 512, 0, stream>>>(hin, hin16, A16, WTT + (size_t)l * 8192,
                                         b_gcn + l * 64, att_s + l * 64, att_d + l * 64,
                                         gh16, asrc, adst);
    k_gat_agg<<<1480, 256, 0, stream>>>(gh16, asrc, adst, csr_soff, offs,
                                        b_gat + l * 64, ln_g + l * 64, ln_b + l * 64,
                                        hin, h, h16);
  }
  // layer 2: dense transform, then fused gather+LN+temporal-conv -> z16
  k_gcn_dense<<<768, 512, 0, stream>>>(h, h16, A16, WTT + (size_t)2 * 8192,
                                       b_gcn + 2 * 64, att_s + 2 * 64, att_d + 2 * 64,
                                       gh16, asrc, adst);
  k_gat_tfuse<<<1480, 256, 0, stream>>>(gh16, asrc, adst, csr_soff, offs,
                                        b_gat + 2 * 64, ln_g + 2 * 64, ln_b + 2 * 64,
                                        h, WB, b_t, z16);

  dim3 g1(NCH_, 2);
  k_mlp1<<<g1, 256, 0, stream>>>(z16, W1, pbuf);
  k_mlp2<<<128, 256, 0, stream>>>(pbuf, b1, W2, b2, outp);
}